// Round 10
// baseline (344.973 us; speedup 1.0000x reference)
//
#include <hip/hip_runtime.h>

#define NN 4096
#define FF 256
#define EE 65536
#define MAXDEG 64
#define MAXEPR 256
#define NCAND 1024

__device__ __forceinline__ int wred_sum(int v) {
#pragma unroll
    for (int o = 32; o >= 1; o >>= 1) v += __shfl_xor(v, o);
    return v;
}
__device__ __forceinline__ double wred_dsum(double v) {
#pragma unroll
    for (int o = 32; o >= 1; o >>= 1) v += __shfl_xor(v, o);
    return v;
}

// ---------------------------------------------------------------------------
// K1: per-row edge-id lists
// ---------------------------------------------------------------------------
__global__ void k_scatter(const int* __restrict__ ei, int* __restrict__ ecnt,
                          int* __restrict__ elist) {
    int e = blockIdx.x * blockDim.x + threadIdx.x;
    if (e >= EE) return;
    int r = ei[e];
    int p = atomicAdd(&ecnt[r], 1);
    if (p < MAXEPR) elist[r * MAXEPR + p] = e;
}

// ---------------------------------------------------------------------------
// K2: sparse CSR build, one 64-thread block per row. Zero only touched LDS
// slots, scatter-add, then dedup via atomicExch claim. Also sq[row] (f64).
// ---------------------------------------------------------------------------
__global__ void k_build(const int* __restrict__ ei, const float* __restrict__ ew,
                        const int* __restrict__ ecnt, const int* __restrict__ elist,
                        const float* __restrict__ X,
                        unsigned short* __restrict__ ccol, float* __restrict__ cval,
                        int* __restrict__ deg, double* __restrict__ sq) {
    __shared__ float row[NN];          // uninitialized; only touched slots used
    __shared__ int cnt;
    const int u = blockIdx.x;
    const int lane = threadIdx.x;      // 64 threads
    if (lane == 0) cnt = 0;

    int ne = ecnt[u]; if (ne > MAXEPR) ne = MAXEPR;
    // pass 1: zero touched columns
    for (int i = lane; i < ne; i += 64) {
        int c = ei[EE + elist[u * MAXEPR + i]];
        if (c != u) row[c] = 0.f;
    }
    __syncthreads();
    // pass 2: accumulate duplicate weights
    for (int i = lane; i < ne; i += 64) {
        int e = elist[u * MAXEPR + i];
        int c = ei[EE + e];
        if (c != u) atomicAdd(&row[c], ew[e]);
    }
    __syncthreads();
    // pass 3: claim each unique column exactly once
    for (int i = lane; i < ne; i += 64) {
        int c = ei[EE + elist[u * MAXEPR + i]];
        if (c != u) {
            float w = atomicExch(&row[c], 0.f);
            if (w != 0.f) {
                int p = atomicAdd(&cnt, 1);
                if (p < MAXDEG) {
                    ccol[u * MAXDEG + p] = (unsigned short)c;
                    cval[u * MAXDEG + p] = fminf(w, 1.f);
                }
            }
        }
    }
    __syncthreads();
    if (lane == 0) deg[u] = cnt;

    // sq[u]
    float4 x4 = ((const float4*)(X + (size_t)u * FF))[lane];
    double s = (double)x4.x * x4.x + (double)x4.y * x4.y +
               (double)x4.z * x4.z + (double)x4.w * x4.w;
    s = wred_dsum(s);
    if (lane == 0) sq[u] = s;
}

// ---------------------------------------------------------------------------
// K3: d_thres = mean(deg) + 2*std(deg), single block
// ---------------------------------------------------------------------------
__global__ void k_stats(const int* __restrict__ deg, double* __restrict__ thres) {
    __shared__ double sd[256], sd2[256];
    int t = threadIdx.x;
    double s = 0, s2 = 0;
    for (int i = t; i < NN; i += 256) {
        double d = (double)deg[i];
        s += d; s2 += d * d;
    }
    sd[t] = s; sd2[t] = s2;
    __syncthreads();
    for (int o = 128; o >= 1; o >>= 1) {
        if (t < o) { sd[t] += sd[t + o]; sd2[t] += sd2[t + o]; }
        __syncthreads();
    }
    if (t == 0) {
        double mean = sd[0] / NN;
        double var = sd2[0] / NN - mean * mean;
        if (var < 0) var = 0;
        thres[0] = mean + 2.0 * sqrt(var);
    }
}

// ---------------------------------------------------------------------------
// K4: A2-row build + candidate compaction + non-rank outputs.
// Rank-case rows: store cidx list, Dr, nz, per-edge (a2v-av); k_dist_d/k_rank
// finish them.
// ---------------------------------------------------------------------------
__launch_bounds__(256, 8)
__global__ void k_a2(const int* __restrict__ ei, const float* __restrict__ ew,
                     const float* __restrict__ th1p, const float* __restrict__ th2p,
                     const unsigned short* __restrict__ ccol,
                     const float* __restrict__ cval, const int* __restrict__ deg,
                     const int* __restrict__ ecnt, const int* __restrict__ elist,
                     const double* __restrict__ thresp,
                     unsigned short* __restrict__ cidx_g, int* __restrict__ drg,
                     int* __restrict__ nzg, float* __restrict__ eadj,
                     float* __restrict__ out) {
    __shared__ float acc[NN];              // 16KB
    __shared__ unsigned short Aucol[MAXDEG];
    __shared__ float Auval[MAXDEG];
    __shared__ int ncand;

    const int u = blockIdx.x;
    const int tid = threadIdx.x;
    const int lane = tid & 63;
    const int wave = tid >> 6;
    const unsigned long long lmask = (1ull << lane) - 1ull;

    const int du = deg[u];
    const int dul = min(du, MAXDEG);
    for (int i = tid; i < NN / 4; i += 256)
        ((float4*)acc)[i] = make_float4(0.f, 0.f, 0.f, 0.f);
    if (tid < dul) {
        Aucol[tid] = ccol[u * MAXDEG + tid];
        Auval[tid] = cval[u * MAXDEG + tid];
    }
    if (tid == 0) ncand = 0;
    __syncthreads();

    // phase A: acc[v] += A'[u][k] * A'[k][v], A' = A + I
    for (int kk = wave; kk <= dul; kk += 4) {
        int k; float wuk;
        if (kk == dul) { k = u; wuk = 1.f; }
        else { k = Aucol[kk]; wuk = Auval[kk]; }
        int dkl = min(deg[k], MAXDEG);
        for (int j = lane; j <= dkl; j += 64) {
            int v; float wkv;
            if (j == dkl) { v = k; wkv = 1.f; }
            else { v = ccol[k * MAXDEG + j]; wkv = cval[k * MAXDEG + j]; }
            atomicAdd(&acc[v], wuk * wkv);
        }
    }
    __syncthreads();
    if (tid == 0) acc[u] = 0.f;
    __syncthreads();

    // phase B: compact candidates to GLOBAL cidx_g
    for (int i4 = tid; i4 < NN / 4; i4 += 256) {
        float4 a4 = ((float4*)acc)[i4];
        float e4[4] = {a4.x, a4.y, a4.z, a4.w};
#pragma unroll
        for (int j = 0; j < 4; ++j) {
            bool nzf = (e4[j] != 0.f);
            unsigned long long m = __ballot(nzf);
            int base = 0;
            if (lane == 0 && m) base = atomicAdd(&ncand, __popcll(m));
            base = __shfl(base, 0);
            int pos = base + __popcll(m & lmask);
            if (nzf && pos < NCAND) cidx_g[u * NCAND + pos] = (unsigned short)(i4 * 4 + j);
        }
    }
    __syncthreads();
    const int Dr = ncand;

    // branch select
    const bool highD = ((double)du > thresp[0]);
    const int nz = Dr - 2 * du;
    const bool rankcase = (!highD) && (nz > 0);
    const float th1 = th1p[0], th2 = th2p[0];
    if (tid == 0) {
        drg[u] = min(Dr, NCAND);
        nzg[u] = rankcase ? nz : 0;
    }

    // per-edge: finalize non-rank rows; stash a2v-av for rank rows
    int ne = ecnt[u]; if (ne > MAXEPR) ne = MAXEPR;
    for (int idx = wave; idx < ne; idx += 4) {
        int e = elist[u * MAXEPR + idx];
        int v = ei[EE + e];                            // wave-uniform
        float w = ew[e];
        float a2v = acc[v];
        // av = A[u][v] via LDS CSR scan
        float avl = 0.f; bool hit = false;
        for (int t = lane; t < dul; t += 64)
            if ((int)Aucol[t] == v) { avl = Auval[t]; hit = true; }
        unsigned long long hm = __ballot(hit);
        float av = hm ? __shfl(avl, (int)__builtin_ctzll(hm)) : 0.f;
        if (rankcase) {
            if (lane == 0) eadj[u * MAXEPR + idx] = a2v - av;
        } else {
            float adj;
            if (highD)       adj = (av != 0.f) ? (a2v - av) : 0.f;
            else if (nz < 0) adj = a2v - av;
            else             adj = 0.f;                // nz == 0
            if (lane == 0) out[e] = fmaxf(0.f, fmaf(th1, w, th2 * adj));
        }
    }
}

// ---------------------------------------------------------------------------
// K5a: distances (rank-case rows). 8-lane-group per candidate:
// each load instruction = 8 groups x 128B contiguous = 8 cache lines for
// 8 candidate rows -- the segment-optimal 8 lines/KB (vs 64 for
// thread-per-candidate scatter). Reduce = 3 shfl_xor levels within group.
// ---------------------------------------------------------------------------
__launch_bounds__(256, 8)
__global__ void k_dist_d(const float* __restrict__ X, const double* __restrict__ sq,
                         const unsigned short* __restrict__ cidx_g,
                         const int* __restrict__ drg, const int* __restrict__ nzg,
                         float* __restrict__ cdist_g) {
    __shared__ float Xu[FF];               // 1KB
    const int u = blockIdx.x;
    if (nzg[u] <= 0) return;
    const int tid = threadIdx.x;
    const int lane = tid & 63;
    const int wave = tid >> 6;
    const int sub = lane & 7;              // position within 8-lane group
    const int grp = lane >> 3;             // candidate slot 0..7
    const int Drs = drg[u];
    const double squ = sq[u];
    const unsigned short* __restrict__ cp = cidx_g + (size_t)u * NCAND;

    if (tid < FF / 4)
        ((float4*)Xu)[tid] = ((const float4*)(X + (size_t)u * FF))[tid];
    __syncthreads();

    // preload this lane's Xu slices: float4 at sub + 8k, k = 0..7 (32 floats)
    float4 xa[8];
#pragma unroll
    for (int k = 0; k < 8; ++k) xa[k] = ((const float4*)Xu)[sub + 8 * k];

    for (int cb = wave * 8; cb < Drs; cb += 32) {
        int ci = cb + grp; if (ci >= Drs) ci = Drs - 1;   // clamp (write guarded)
        int v = (int)cp[ci];
        const float4* __restrict__ Xv = (const float4*)(X + (size_t)v * FF);
        double s0 = 0.0, s1 = 0.0;
#pragma unroll
        for (int k = 0; k < 8; k += 2) {
            float4 a = Xv[sub + 8 * k];
            float4 b = xa[k];
            s0 += (double)a.x * b.x + (double)a.y * b.y +
                  (double)a.z * b.z + (double)a.w * b.w;
            float4 p = Xv[sub + 8 * (k + 1)];
            float4 q = xa[k + 1];
            s1 += (double)p.x * q.x + (double)p.y * q.y +
                  (double)p.z * q.z + (double)p.w * q.w;
        }
        double s = s0 + s1;
        s += __shfl_xor(s, 1);
        s += __shfl_xor(s, 2);
        s += __shfl_xor(s, 4);
        if (sub == 0 && cb + grp < Drs)
            cdist_g[(size_t)u * NCAND + ci] = (float)(squ + sq[v] - 2.0 * s);
    }
}

// ---------------------------------------------------------------------------
// K5b: per-edge rank + output (rank-case rows).
// ---------------------------------------------------------------------------
__launch_bounds__(256, 8)
__global__ void k_rank(const int* __restrict__ ei, const float* __restrict__ ew,
                       const float* __restrict__ th1p, const float* __restrict__ th2p,
                       const int* __restrict__ ecnt, const int* __restrict__ elist,
                       const unsigned short* __restrict__ cidx_g,
                       const float* __restrict__ cdist_g,
                       const int* __restrict__ drg, const int* __restrict__ nzg,
                       const float* __restrict__ eadj, float* __restrict__ out) {
    __shared__ unsigned short cidx[NCAND]; // 2KB
    __shared__ float cdist[NCAND];         // 4KB

    const int u = blockIdx.x;
    const int nz = nzg[u];
    if (nz <= 0) return;
    const int tid = threadIdx.x;
    const int lane = tid & 63;
    const int wave = tid >> 6;

    const int Drs = drg[u];
    for (int i = tid; i < Drs; i += 256) {
        cidx[i] = cidx_g[u * NCAND + i];
        cdist[i] = cdist_g[u * NCAND + i];
    }
    __syncthreads();

    const float th1 = th1p[0], th2 = th2p[0];
    int ne = ecnt[u]; if (ne > MAXEPR) ne = MAXEPR;
    for (int idx = wave; idx < ne; idx += 4) {
        int e = elist[u * MAXEPR + idx];
        int v = ei[EE + e];                            // wave-uniform
        float w = ew[e];
        // dv lookup
        float dvl = 0.f; bool fnd = false;
        for (int c = lane; c < Drs; c += 64)
            if ((int)cidx[c] == v) { dvl = cdist[c]; fnd = true; }
        unsigned long long fm = __ballot(fnd);
        float dv = __shfl(dvl, (int)__builtin_ctzll(fm));
        // stable descending rank of v among candidates
        int cnt = 0;
        for (int c = lane; c < Drs; c += 64) {
            float cd = cdist[c];
            int ci = cidx[c];
            cnt += (cd > dv || (cd == dv && ci < v)) ? 1 : 0;
        }
        cnt = wred_sum(cnt);
        float adj = (cnt < nz) ? 0.f : eadj[u * MAXEPR + idx];
        if (lane == 0) out[e] = fmaxf(0.f, fmaf(th1, w, th2 * adj));
    }
}

// ---------------------------------------------------------------------------
extern "C" void kernel_launch(void* const* d_in, const int* in_sizes, int n_in,
                              void* d_out, int out_size, void* d_ws, size_t ws_size,
                              hipStream_t stream) {
    const int* ei = (const int*)d_in[0];
    const float* ew = (const float*)d_in[1];
    const float* X = (const float*)d_in[2];
    const float* th1 = (const float*)d_in[3];
    const float* th2 = (const float*)d_in[4];
    float* out = (float*)d_out;

    char* ws = (char*)d_ws;
    size_t off = 0;
    unsigned short* ccol = (unsigned short*)(ws + off); off += (size_t)NN * MAXDEG * 2;
    float* cval = (float*)(ws + off);          off += (size_t)NN * MAXDEG * 4;
    int* deg = (int*)(ws + off);               off += (size_t)NN * 4;
    int* ecnt = (int*)(ws + off);              off += (size_t)NN * 4;
    double* sq = (double*)(ws + off);          off += (size_t)NN * 8;
    double* thres = (double*)(ws + off);       off += 256;
    int* elist = (int*)(ws + off);             off += (size_t)NN * MAXEPR * 4;
    unsigned short* cidx_g = (unsigned short*)(ws + off); off += (size_t)NN * NCAND * 2;
    int* drg = (int*)(ws + off);               off += (size_t)NN * 4;
    int* nzg = (int*)(ws + off);               off += (size_t)NN * 4;
    float* eadj = (float*)(ws + off);          off += (size_t)NN * MAXEPR * 4;
    float* cdist_g = (float*)(ws + off);       off += (size_t)NN * NCAND * 4;

    hipMemsetAsync(ecnt, 0, (size_t)NN * 4, stream);

    k_scatter<<<EE / 256, 256, 0, stream>>>(ei, ecnt, elist);
    k_build<<<NN, 64, 0, stream>>>(ei, ew, ecnt, elist, X, ccol, cval, deg, sq);
    k_stats<<<1, 256, 0, stream>>>(deg, thres);
    k_a2<<<NN, 256, 0, stream>>>(ei, ew, th1, th2, ccol, cval, deg, ecnt, elist,
                                 thres, cidx_g, drg, nzg, eadj, out);
    k_dist_d<<<NN, 256, 0, stream>>>(X, sq, cidx_g, drg, nzg, cdist_g);
    k_rank<<<NN, 256, 0, stream>>>(ei, ew, th1, th2, ecnt, elist,
                                   cidx_g, cdist_g, drg, nzg, eadj, out);
}

// Round 11
// 344.393 us; speedup vs baseline: 1.0017x; 1.0017x over previous
//
#include <hip/hip_runtime.h>

#define NN 4096
#define FF 256
#define EE 65536
#define MAXDEG 64
#define MAXEPR 256
#define NCAND 1024

__device__ __forceinline__ int wred_sum(int v) {
#pragma unroll
    for (int o = 32; o >= 1; o >>= 1) v += __shfl_xor(v, o);
    return v;
}
__device__ __forceinline__ double wred_dsum(double v) {
#pragma unroll
    for (int o = 32; o >= 1; o >>= 1) v += __shfl_xor(v, o);
    return v;
}

// ---------------------------------------------------------------------------
// K1: per-row edge-id lists
// ---------------------------------------------------------------------------
__global__ void k_scatter(const int* __restrict__ ei, int* __restrict__ ecnt,
                          int* __restrict__ elist) {
    int e = blockIdx.x * blockDim.x + threadIdx.x;
    if (e >= EE) return;
    int r = ei[e];
    int p = atomicAdd(&ecnt[r], 1);
    if (p < MAXEPR) elist[r * MAXEPR + p] = e;
}

// ---------------------------------------------------------------------------
// K2: sparse CSR build, one 64-thread block per row. Zero only touched LDS
// slots, scatter-add, then dedup via atomicExch claim. Also sq[row] (f64).
// ---------------------------------------------------------------------------
__global__ void k_build(const int* __restrict__ ei, const float* __restrict__ ew,
                        const int* __restrict__ ecnt, const int* __restrict__ elist,
                        const float* __restrict__ X,
                        unsigned short* __restrict__ ccol, float* __restrict__ cval,
                        int* __restrict__ deg, double* __restrict__ sq) {
    __shared__ float row[NN];          // uninitialized; only touched slots used
    __shared__ int cnt;
    const int u = blockIdx.x;
    const int lane = threadIdx.x;      // 64 threads
    if (lane == 0) cnt = 0;

    int ne = ecnt[u]; if (ne > MAXEPR) ne = MAXEPR;
    // pass 1: zero touched columns
    for (int i = lane; i < ne; i += 64) {
        int c = ei[EE + elist[u * MAXEPR + i]];
        if (c != u) row[c] = 0.f;
    }
    __syncthreads();
    // pass 2: accumulate duplicate weights
    for (int i = lane; i < ne; i += 64) {
        int e = elist[u * MAXEPR + i];
        int c = ei[EE + e];
        if (c != u) atomicAdd(&row[c], ew[e]);
    }
    __syncthreads();
    // pass 3: claim each unique column exactly once
    for (int i = lane; i < ne; i += 64) {
        int c = ei[EE + elist[u * MAXEPR + i]];
        if (c != u) {
            float w = atomicExch(&row[c], 0.f);
            if (w != 0.f) {
                int p = atomicAdd(&cnt, 1);
                if (p < MAXDEG) {
                    ccol[u * MAXDEG + p] = (unsigned short)c;
                    cval[u * MAXDEG + p] = fminf(w, 1.f);
                }
            }
        }
    }
    __syncthreads();
    if (lane == 0) deg[u] = cnt;

    // sq[u]
    float4 x4 = ((const float4*)(X + (size_t)u * FF))[lane];
    double s = (double)x4.x * x4.x + (double)x4.y * x4.y +
               (double)x4.z * x4.z + (double)x4.w * x4.w;
    s = wred_dsum(s);
    if (lane == 0) sq[u] = s;
}

// ---------------------------------------------------------------------------
// K3: d_thres = mean(deg) + 2*std(deg), single block
// ---------------------------------------------------------------------------
__global__ void k_stats(const int* __restrict__ deg, double* __restrict__ thres) {
    __shared__ double sd[256], sd2[256];
    int t = threadIdx.x;
    double s = 0, s2 = 0;
    for (int i = t; i < NN; i += 256) {
        double d = (double)deg[i];
        s += d; s2 += d * d;
    }
    sd[t] = s; sd2[t] = s2;
    __syncthreads();
    for (int o = 128; o >= 1; o >>= 1) {
        if (t < o) { sd[t] += sd[t + o]; sd2[t] += sd2[t + o]; }
        __syncthreads();
    }
    if (t == 0) {
        double mean = sd[0] / NN;
        double var = sd2[0] / NN - mean * mean;
        if (var < 0) var = 0;
        thres[0] = mean + 2.0 * sqrt(var);
    }
}

// ---------------------------------------------------------------------------
// K4: A2-row build + candidate compaction + non-rank outputs.
// Rank-case rows: store cidx list, Dr, nz, per-edge (a2v-av); k_dist_d/k_rank
// finish them.
// ---------------------------------------------------------------------------
__launch_bounds__(256, 8)
__global__ void k_a2(const int* __restrict__ ei, const float* __restrict__ ew,
                     const float* __restrict__ th1p, const float* __restrict__ th2p,
                     const unsigned short* __restrict__ ccol,
                     const float* __restrict__ cval, const int* __restrict__ deg,
                     const int* __restrict__ ecnt, const int* __restrict__ elist,
                     const double* __restrict__ thresp,
                     unsigned short* __restrict__ cidx_g, int* __restrict__ drg,
                     int* __restrict__ nzg, float* __restrict__ eadj,
                     float* __restrict__ out) {
    __shared__ float acc[NN];              // 16KB
    __shared__ unsigned short Aucol[MAXDEG];
    __shared__ float Auval[MAXDEG];
    __shared__ int ncand;

    const int u = blockIdx.x;
    const int tid = threadIdx.x;
    const int lane = tid & 63;
    const int wave = tid >> 6;
    const unsigned long long lmask = (1ull << lane) - 1ull;

    const int du = deg[u];
    const int dul = min(du, MAXDEG);
    for (int i = tid; i < NN / 4; i += 256)
        ((float4*)acc)[i] = make_float4(0.f, 0.f, 0.f, 0.f);
    if (tid < dul) {
        Aucol[tid] = ccol[u * MAXDEG + tid];
        Auval[tid] = cval[u * MAXDEG + tid];
    }
    if (tid == 0) ncand = 0;
    __syncthreads();

    // phase A: acc[v] += A'[u][k] * A'[k][v], A' = A + I
    for (int kk = wave; kk <= dul; kk += 4) {
        int k; float wuk;
        if (kk == dul) { k = u; wuk = 1.f; }
        else { k = Aucol[kk]; wuk = Auval[kk]; }
        int dkl = min(deg[k], MAXDEG);
        for (int j = lane; j <= dkl; j += 64) {
            int v; float wkv;
            if (j == dkl) { v = k; wkv = 1.f; }
            else { v = ccol[k * MAXDEG + j]; wkv = cval[k * MAXDEG + j]; }
            atomicAdd(&acc[v], wuk * wkv);
        }
    }
    __syncthreads();
    if (tid == 0) acc[u] = 0.f;
    __syncthreads();

    // phase B: compact candidates to GLOBAL cidx_g
    for (int i4 = tid; i4 < NN / 4; i4 += 256) {
        float4 a4 = ((float4*)acc)[i4];
        float e4[4] = {a4.x, a4.y, a4.z, a4.w};
#pragma unroll
        for (int j = 0; j < 4; ++j) {
            bool nzf = (e4[j] != 0.f);
            unsigned long long m = __ballot(nzf);
            int base = 0;
            if (lane == 0 && m) base = atomicAdd(&ncand, __popcll(m));
            base = __shfl(base, 0);
            int pos = base + __popcll(m & lmask);
            if (nzf && pos < NCAND) cidx_g[u * NCAND + pos] = (unsigned short)(i4 * 4 + j);
        }
    }
    __syncthreads();
    const int Dr = ncand;

    // branch select
    const bool highD = ((double)du > thresp[0]);
    const int nz = Dr - 2 * du;
    const bool rankcase = (!highD) && (nz > 0);
    const float th1 = th1p[0], th2 = th2p[0];
    if (tid == 0) {
        drg[u] = min(Dr, NCAND);
        nzg[u] = rankcase ? nz : 0;
    }

    // per-edge: finalize non-rank rows; stash a2v-av for rank rows
    int ne = ecnt[u]; if (ne > MAXEPR) ne = MAXEPR;
    for (int idx = wave; idx < ne; idx += 4) {
        int e = elist[u * MAXEPR + idx];
        int v = ei[EE + e];                            // wave-uniform
        float w = ew[e];
        float a2v = acc[v];
        // av = A[u][v] via LDS CSR scan
        float avl = 0.f; bool hit = false;
        for (int t = lane; t < dul; t += 64)
            if ((int)Aucol[t] == v) { avl = Auval[t]; hit = true; }
        unsigned long long hm = __ballot(hit);
        float av = hm ? __shfl(avl, (int)__builtin_ctzll(hm)) : 0.f;
        if (rankcase) {
            if (lane == 0) eadj[u * MAXEPR + idx] = a2v - av;
        } else {
            float adj;
            if (highD)       adj = (av != 0.f) ? (a2v - av) : 0.f;
            else if (nz < 0) adj = a2v - av;
            else             adj = 0.f;                // nz == 0
            if (lane == 0) out[e] = fmaxf(0.f, fmaf(th1, w, th2 * adj));
        }
    }
}

// ---------------------------------------------------------------------------
// K5a: distances (rank-case rows). 8-lane-group per candidate: each global
// load instruction = 8 groups x 128B contiguous = 8 cache lines for 8
// candidate rows (segment-optimal; R9's thread-per-cand was 64 lines/instr).
// Xu operand read from LDS inside the loop (broadcast, no registers held)
// -- R10's xa[8] register preload spilled to scratch (110MB writes) and is
// removed.
// ---------------------------------------------------------------------------
__launch_bounds__(256, 8)
__global__ void k_dist_d(const float* __restrict__ X, const double* __restrict__ sq,
                         const unsigned short* __restrict__ cidx_g,
                         const int* __restrict__ drg, const int* __restrict__ nzg,
                         float* __restrict__ cdist_g) {
    __shared__ float Xu[FF];               // 1KB
    const int u = blockIdx.x;
    if (nzg[u] <= 0) return;
    const int tid = threadIdx.x;
    const int lane = tid & 63;
    const int wave = tid >> 6;
    const int sub = lane & 7;              // position within 8-lane group
    const int grp = lane >> 3;             // candidate slot 0..7
    const int Drs = drg[u];
    const double squ = sq[u];
    const unsigned short* __restrict__ cp = cidx_g + (size_t)u * NCAND;

    if (tid < FF / 4)
        ((float4*)Xu)[tid] = ((const float4*)(X + (size_t)u * FF))[tid];
    __syncthreads();

    const float4* __restrict__ XuV = (const float4*)Xu;
    for (int cb = wave * 8; cb < Drs; cb += 32) {
        int ci = cb + grp; if (ci >= Drs) ci = Drs - 1;   // clamp (write guarded)
        int v = (int)cp[ci];
        const float4* __restrict__ Xv = (const float4*)(X + (size_t)v * FF);
        double s0 = 0.0, s1 = 0.0;
#pragma unroll
        for (int k = 0; k < 8; k += 2) {
            float4 a = Xv[sub + 8 * k];
            float4 b = XuV[sub + 8 * k];            // LDS broadcast read
            s0 += (double)a.x * b.x + (double)a.y * b.y +
                  (double)a.z * b.z + (double)a.w * b.w;
            float4 p = Xv[sub + 8 * (k + 1)];
            float4 q = XuV[sub + 8 * (k + 1)];
            s1 += (double)p.x * q.x + (double)p.y * q.y +
                  (double)p.z * q.z + (double)p.w * q.w;
        }
        double s = s0 + s1;
        s += __shfl_xor(s, 1);
        s += __shfl_xor(s, 2);
        s += __shfl_xor(s, 4);
        if (sub == 0 && cb + grp < Drs)
            cdist_g[(size_t)u * NCAND + ci] = (float)(squ + sq[v] - 2.0 * s);
    }
}

// ---------------------------------------------------------------------------
// K5b: per-edge rank + output (rank-case rows).
// ---------------------------------------------------------------------------
__launch_bounds__(256, 8)
__global__ void k_rank(const int* __restrict__ ei, const float* __restrict__ ew,
                       const float* __restrict__ th1p, const float* __restrict__ th2p,
                       const int* __restrict__ ecnt, const int* __restrict__ elist,
                       const unsigned short* __restrict__ cidx_g,
                       const float* __restrict__ cdist_g,
                       const int* __restrict__ drg, const int* __restrict__ nzg,
                       const float* __restrict__ eadj, float* __restrict__ out) {
    __shared__ unsigned short cidx[NCAND]; // 2KB
    __shared__ float cdist[NCAND];         // 4KB

    const int u = blockIdx.x;
    const int nz = nzg[u];
    if (nz <= 0) return;
    const int tid = threadIdx.x;
    const int lane = tid & 63;
    const int wave = tid >> 6;

    const int Drs = drg[u];
    for (int i = tid; i < Drs; i += 256) {
        cidx[i] = cidx_g[u * NCAND + i];
        cdist[i] = cdist_g[u * NCAND + i];
    }
    __syncthreads();

    const float th1 = th1p[0], th2 = th2p[0];
    int ne = ecnt[u]; if (ne > MAXEPR) ne = MAXEPR;
    for (int idx = wave; idx < ne; idx += 4) {
        int e = elist[u * MAXEPR + idx];
        int v = ei[EE + e];                            // wave-uniform
        float w = ew[e];
        // dv lookup
        float dvl = 0.f; bool fnd = false;
        for (int c = lane; c < Drs; c += 64)
            if ((int)cidx[c] == v) { dvl = cdist[c]; fnd = true; }
        unsigned long long fm = __ballot(fnd);
        float dv = __shfl(dvl, (int)__builtin_ctzll(fm));
        // stable descending rank of v among candidates
        int cnt = 0;
        for (int c = lane; c < Drs; c += 64) {
            float cd = cdist[c];
            int ci = cidx[c];
            cnt += (cd > dv || (cd == dv && ci < v)) ? 1 : 0;
        }
        cnt = wred_sum(cnt);
        float adj = (cnt < nz) ? 0.f : eadj[u * MAXEPR + idx];
        if (lane == 0) out[e] = fmaxf(0.f, fmaf(th1, w, th2 * adj));
    }
}

// ---------------------------------------------------------------------------
extern "C" void kernel_launch(void* const* d_in, const int* in_sizes, int n_in,
                              void* d_out, int out_size, void* d_ws, size_t ws_size,
                              hipStream_t stream) {
    const int* ei = (const int*)d_in[0];
    const float* ew = (const float*)d_in[1];
    const float* X = (const float*)d_in[2];
    const float* th1 = (const float*)d_in[3];
    const float* th2 = (const float*)d_in[4];
    float* out = (float*)d_out;

    char* ws = (char*)d_ws;
    size_t off = 0;
    unsigned short* ccol = (unsigned short*)(ws + off); off += (size_t)NN * MAXDEG * 2;
    float* cval = (float*)(ws + off);          off += (size_t)NN * MAXDEG * 4;
    int* deg = (int*)(ws + off);               off += (size_t)NN * 4;
    int* ecnt = (int*)(ws + off);              off += (size_t)NN * 4;
    double* sq = (double*)(ws + off);          off += (size_t)NN * 8;
    double* thres = (double*)(ws + off);       off += 256;
    int* elist = (int*)(ws + off);             off += (size_t)NN * MAXEPR * 4;
    unsigned short* cidx_g = (unsigned short*)(ws + off); off += (size_t)NN * NCAND * 2;
    int* drg = (int*)(ws + off);               off += (size_t)NN * 4;
    int* nzg = (int*)(ws + off);               off += (size_t)NN * 4;
    float* eadj = (float*)(ws + off);          off += (size_t)NN * MAXEPR * 4;
    float* cdist_g = (float*)(ws + off);       off += (size_t)NN * NCAND * 4;

    hipMemsetAsync(ecnt, 0, (size_t)NN * 4, stream);

    k_scatter<<<EE / 256, 256, 0, stream>>>(ei, ecnt, elist);
    k_build<<<NN, 64, 0, stream>>>(ei, ew, ecnt, elist, X, ccol, cval, deg, sq);
    k_stats<<<1, 256, 0, stream>>>(deg, thres);
    k_a2<<<NN, 256, 0, stream>>>(ei, ew, th1, th2, ccol, cval, deg, ecnt, elist,
                                 thres, cidx_g, drg, nzg, eadj, out);
    k_dist_d<<<NN, 256, 0, stream>>>(X, sq, cidx_g, drg, nzg, cdist_g);
    k_rank<<<NN, 256, 0, stream>>>(ei, ew, th1, th2, ecnt, elist,
                                   cidx_g, cdist_g, drg, nzg, eadj, out);
}

// Round 12
// 272.517 us; speedup vs baseline: 1.2659x; 1.2637x over previous
//
#include <hip/hip_runtime.h>

#define NN 4096
#define FF 256
#define EE 65536
#define MAXDEG 64
#define MAXEPR 256
#define NCAND 1024

__device__ __forceinline__ int wred_sum(int v) {
#pragma unroll
    for (int o = 32; o >= 1; o >>= 1) v += __shfl_xor(v, o);
    return v;
}
__device__ __forceinline__ double wred_dsum(double v) {
#pragma unroll
    for (int o = 32; o >= 1; o >>= 1) v += __shfl_xor(v, o);
    return v;
}

// ---------------------------------------------------------------------------
// K1: per-row edge-id lists
// ---------------------------------------------------------------------------
__global__ void k_scatter(const int* __restrict__ ei, int* __restrict__ ecnt,
                          int* __restrict__ elist) {
    int e = blockIdx.x * blockDim.x + threadIdx.x;
    if (e >= EE) return;
    int r = ei[e];
    int p = atomicAdd(&ecnt[r], 1);
    if (p < MAXEPR) elist[r * MAXEPR + p] = e;
}

// ---------------------------------------------------------------------------
// K2: sparse CSR build, one 64-thread block per row. Zero only touched LDS
// slots, scatter-add, then dedup via atomicExch claim. Also sq[row] (f64).
// ---------------------------------------------------------------------------
__global__ void k_build(const int* __restrict__ ei, const float* __restrict__ ew,
                        const int* __restrict__ ecnt, const int* __restrict__ elist,
                        const float* __restrict__ X,
                        unsigned short* __restrict__ ccol, float* __restrict__ cval,
                        int* __restrict__ deg, double* __restrict__ sq) {
    __shared__ float row[NN];          // uninitialized; only touched slots used
    __shared__ int cnt;
    const int u = blockIdx.x;
    const int lane = threadIdx.x;      // 64 threads
    if (lane == 0) cnt = 0;

    int ne = ecnt[u]; if (ne > MAXEPR) ne = MAXEPR;
    // pass 1: zero touched columns
    for (int i = lane; i < ne; i += 64) {
        int c = ei[EE + elist[u * MAXEPR + i]];
        if (c != u) row[c] = 0.f;
    }
    __syncthreads();
    // pass 2: accumulate duplicate weights
    for (int i = lane; i < ne; i += 64) {
        int e = elist[u * MAXEPR + i];
        int c = ei[EE + e];
        if (c != u) atomicAdd(&row[c], ew[e]);
    }
    __syncthreads();
    // pass 3: claim each unique column exactly once
    for (int i = lane; i < ne; i += 64) {
        int c = ei[EE + elist[u * MAXEPR + i]];
        if (c != u) {
            float w = atomicExch(&row[c], 0.f);
            if (w != 0.f) {
                int p = atomicAdd(&cnt, 1);
                if (p < MAXDEG) {
                    ccol[u * MAXDEG + p] = (unsigned short)c;
                    cval[u * MAXDEG + p] = fminf(w, 1.f);
                }
            }
        }
    }
    __syncthreads();
    if (lane == 0) deg[u] = cnt;

    // sq[u]
    float4 x4 = ((const float4*)(X + (size_t)u * FF))[lane];
    double s = (double)x4.x * x4.x + (double)x4.y * x4.y +
               (double)x4.z * x4.z + (double)x4.w * x4.w;
    s = wred_dsum(s);
    if (lane == 0) sq[u] = s;
}

// ---------------------------------------------------------------------------
// K3: d_thres = mean(deg) + 2*std(deg), single block
// ---------------------------------------------------------------------------
__global__ void k_stats(const int* __restrict__ deg, double* __restrict__ thres) {
    __shared__ double sd[256], sd2[256];
    int t = threadIdx.x;
    double s = 0, s2 = 0;
    for (int i = t; i < NN; i += 256) {
        double d = (double)deg[i];
        s += d; s2 += d * d;
    }
    sd[t] = s; sd2[t] = s2;
    __syncthreads();
    for (int o = 128; o >= 1; o >>= 1) {
        if (t < o) { sd[t] += sd[t + o]; sd2[t] += sd2[t + o]; }
        __syncthreads();
    }
    if (t == 0) {
        double mean = sd[0] / NN;
        double var = sd2[0] / NN - mean * mean;
        if (var < 0) var = 0;
        thres[0] = mean + 2.0 * sqrt(var);
    }
}

// ---------------------------------------------------------------------------
// K4: A2-row build + candidate compaction + non-rank outputs.
// Rank-case rows: store cidx list, Dr, nz, per-edge (a2v-av); k_dist finishes.
// ---------------------------------------------------------------------------
__launch_bounds__(256, 8)
__global__ void k_a2(const int* __restrict__ ei, const float* __restrict__ ew,
                     const float* __restrict__ th1p, const float* __restrict__ th2p,
                     const unsigned short* __restrict__ ccol,
                     const float* __restrict__ cval, const int* __restrict__ deg,
                     const int* __restrict__ ecnt, const int* __restrict__ elist,
                     const double* __restrict__ thresp,
                     unsigned short* __restrict__ cidx_g, int* __restrict__ drg,
                     int* __restrict__ nzg, float* __restrict__ eadj,
                     float* __restrict__ out) {
    __shared__ float acc[NN];              // 16KB
    __shared__ unsigned short Aucol[MAXDEG];
    __shared__ float Auval[MAXDEG];
    __shared__ int ncand;

    const int u = blockIdx.x;
    const int tid = threadIdx.x;
    const int lane = tid & 63;
    const int wave = tid >> 6;
    const unsigned long long lmask = (1ull << lane) - 1ull;

    const int du = deg[u];
    const int dul = min(du, MAXDEG);
    for (int i = tid; i < NN / 4; i += 256)
        ((float4*)acc)[i] = make_float4(0.f, 0.f, 0.f, 0.f);
    if (tid < dul) {
        Aucol[tid] = ccol[u * MAXDEG + tid];
        Auval[tid] = cval[u * MAXDEG + tid];
    }
    if (tid == 0) ncand = 0;
    __syncthreads();

    // phase A: acc[v] += A'[u][k] * A'[k][v], A' = A + I
    for (int kk = wave; kk <= dul; kk += 4) {
        int k; float wuk;
        if (kk == dul) { k = u; wuk = 1.f; }
        else { k = Aucol[kk]; wuk = Auval[kk]; }
        int dkl = min(deg[k], MAXDEG);
        for (int j = lane; j <= dkl; j += 64) {
            int v; float wkv;
            if (j == dkl) { v = k; wkv = 1.f; }
            else { v = ccol[k * MAXDEG + j]; wkv = cval[k * MAXDEG + j]; }
            atomicAdd(&acc[v], wuk * wkv);
        }
    }
    __syncthreads();
    if (tid == 0) acc[u] = 0.f;
    __syncthreads();

    // phase B: compact candidates to GLOBAL cidx_g
    for (int i4 = tid; i4 < NN / 4; i4 += 256) {
        float4 a4 = ((float4*)acc)[i4];
        float e4[4] = {a4.x, a4.y, a4.z, a4.w};
#pragma unroll
        for (int j = 0; j < 4; ++j) {
            bool nzf = (e4[j] != 0.f);
            unsigned long long m = __ballot(nzf);
            int base = 0;
            if (lane == 0 && m) base = atomicAdd(&ncand, __popcll(m));
            base = __shfl(base, 0);
            int pos = base + __popcll(m & lmask);
            if (nzf && pos < NCAND) cidx_g[u * NCAND + pos] = (unsigned short)(i4 * 4 + j);
        }
    }
    __syncthreads();
    const int Dr = ncand;

    // branch select
    const bool highD = ((double)du > thresp[0]);
    const int nz = Dr - 2 * du;
    const bool rankcase = (!highD) && (nz > 0);
    const float th1 = th1p[0], th2 = th2p[0];
    if (tid == 0) {
        drg[u] = min(Dr, NCAND);
        nzg[u] = rankcase ? nz : 0;
    }

    // per-edge: finalize non-rank rows; stash a2v-av for rank rows
    int ne = ecnt[u]; if (ne > MAXEPR) ne = MAXEPR;
    for (int idx = wave; idx < ne; idx += 4) {
        int e = elist[u * MAXEPR + idx];
        int v = ei[EE + e];                            // wave-uniform
        float w = ew[e];
        float a2v = acc[v];
        // av = A[u][v] via LDS CSR scan
        float avl = 0.f; bool hit = false;
        for (int t = lane; t < dul; t += 64)
            if ((int)Aucol[t] == v) { avl = Auval[t]; hit = true; }
        unsigned long long hm = __ballot(hit);
        float av = hm ? __shfl(avl, (int)__builtin_ctzll(hm)) : 0.f;
        if (rankcase) {
            if (lane == 0) eadj[u * MAXEPR + idx] = a2v - av;
        } else {
            float adj;
            if (highD)       adj = (av != 0.f) ? (a2v - av) : 0.f;
            else if (nz < 0) adj = a2v - av;
            else             adj = 0.f;                // nz == 0
            if (lane == 0) out[e] = fmaxf(0.f, fmaf(th1, w, th2 * adj));
        }
    }
}

// ---------------------------------------------------------------------------
// K5: distances + rank for rank-case rows only. Thread-per-candidate
// sequential row walk: cache-optimal (R9 counters: FETCH 28MB = one cold
// pass of X per XCD, then 100% L2 hits). Sits at the measured ~0.6
// 16B-requests/cy/CU scattered-gather ceiling; restructures (R8/R10/R11)
// all regressed by breaking L2 residency.
// ---------------------------------------------------------------------------
__launch_bounds__(256, 8)
__global__ void k_dist(const int* __restrict__ ei, const float* __restrict__ ew,
                       const float* __restrict__ X, const float* __restrict__ th1p,
                       const float* __restrict__ th2p,
                       const int* __restrict__ ecnt, const int* __restrict__ elist,
                       const double* __restrict__ sq,
                       const unsigned short* __restrict__ cidx_g,
                       const int* __restrict__ drg, const int* __restrict__ nzg,
                       const float* __restrict__ eadj, float* __restrict__ out) {
    __shared__ float Xu[FF];               // 1KB
    __shared__ unsigned short cidx[NCAND]; // 2KB
    __shared__ float cdist[NCAND];         // 4KB

    const int u = blockIdx.x;
    const int nz = nzg[u];
    if (nz <= 0) return;                   // non-rank rows fully handled by k_a2
    const int tid = threadIdx.x;
    const int lane = tid & 63;
    const int wave = tid >> 6;

    const int Drs = drg[u];
    if (tid < FF / 4)
        ((float4*)Xu)[tid] = ((const float4*)(X + (size_t)u * FF))[tid];
    for (int i = tid; i < Drs; i += 256) cidx[i] = cidx_g[u * NCAND + i];
    __syncthreads();

    // distances: one candidate per thread, 2-chain f64 (proven 44-VGPR form)
    const double squ = sq[u];
    for (int c = tid; c < Drs; c += 256) {
        int v = cidx[c];
        const float4* __restrict__ Xv = (const float4*)(X + (size_t)v * FF);
        double sqv = sq[v];
        double s0 = 0.0, s1 = 0.0;
#pragma unroll 4
        for (int f = 0; f < FF / 4; f += 2) {
            float4 a = Xv[f];
            float4 b = ((const float4*)Xu)[f];
            s0 += (double)a.x * b.x + (double)a.y * b.y +
                  (double)a.z * b.z + (double)a.w * b.w;
            float4 p = Xv[f + 1];
            float4 q = ((const float4*)Xu)[f + 1];
            s1 += (double)p.x * q.x + (double)p.y * q.y +
                  (double)p.z * q.z + (double)p.w * q.w;
        }
        cdist[c] = (float)(squ + sqv - 2.0 * (s0 + s1));
    }
    __syncthreads();

    // per-edge: one wave per edge; stable descending rank of v
    const float th1 = th1p[0], th2 = th2p[0];
    int ne = ecnt[u]; if (ne > MAXEPR) ne = MAXEPR;
    for (int idx = wave; idx < ne; idx += 4) {
        int e = elist[u * MAXEPR + idx];
        int v = ei[EE + e];                            // wave-uniform
        float w = ew[e];
        // dv lookup
        float dvl = 0.f; bool fnd = false;
        for (int c = lane; c < Drs; c += 64)
            if ((int)cidx[c] == v) { dvl = cdist[c]; fnd = true; }
        unsigned long long fm = __ballot(fnd);
        float dv = __shfl(dvl, (int)__builtin_ctzll(fm));
        // rank count
        int cnt = 0;
        for (int c = lane; c < Drs; c += 64) {
            float cd = cdist[c];
            int ci = cidx[c];
            cnt += (cd > dv || (cd == dv && ci < v)) ? 1 : 0;
        }
        cnt = wred_sum(cnt);
        float adj = (cnt < nz) ? 0.f : eadj[u * MAXEPR + idx];
        if (lane == 0) out[e] = fmaxf(0.f, fmaf(th1, w, th2 * adj));
    }
}

// ---------------------------------------------------------------------------
extern "C" void kernel_launch(void* const* d_in, const int* in_sizes, int n_in,
                              void* d_out, int out_size, void* d_ws, size_t ws_size,
                              hipStream_t stream) {
    const int* ei = (const int*)d_in[0];
    const float* ew = (const float*)d_in[1];
    const float* X = (const float*)d_in[2];
    const float* th1 = (const float*)d_in[3];
    const float* th2 = (const float*)d_in[4];
    float* out = (float*)d_out;

    char* ws = (char*)d_ws;
    size_t off = 0;
    unsigned short* ccol = (unsigned short*)(ws + off); off += (size_t)NN * MAXDEG * 2;
    float* cval = (float*)(ws + off);          off += (size_t)NN * MAXDEG * 4;
    int* deg = (int*)(ws + off);               off += (size_t)NN * 4;
    int* ecnt = (int*)(ws + off);              off += (size_t)NN * 4;
    double* sq = (double*)(ws + off);          off += (size_t)NN * 8;
    double* thres = (double*)(ws + off);       off += 256;
    int* elist = (int*)(ws + off);             off += (size_t)NN * MAXEPR * 4;
    unsigned short* cidx_g = (unsigned short*)(ws + off); off += (size_t)NN * NCAND * 2;
    int* drg = (int*)(ws + off);               off += (size_t)NN * 4;
    int* nzg = (int*)(ws + off);               off += (size_t)NN * 4;
    float* eadj = (float*)(ws + off);          off += (size_t)NN * MAXEPR * 4;

    hipMemsetAsync(ecnt, 0, (size_t)NN * 4, stream);

    k_scatter<<<EE / 256, 256, 0, stream>>>(ei, ecnt, elist);
    k_build<<<NN, 64, 0, stream>>>(ei, ew, ecnt, elist, X, ccol, cval, deg, sq);
    k_stats<<<1, 256, 0, stream>>>(deg, thres);
    k_a2<<<NN, 256, 0, stream>>>(ei, ew, th1, th2, ccol, cval, deg, ecnt, elist,
                                 thres, cidx_g, drg, nzg, eadj, out);
    k_dist<<<NN, 256, 0, stream>>>(ei, ew, X, th1, th2, ecnt, elist, sq,
                                   cidx_g, drg, nzg, eadj, out);
}